// Round 8
// baseline (367.623 us; speedup 1.0000x reference)
//
#include <hip/hip_runtime.h>

#define N_CELL 200000
#define N_WELL 2000
#define E_CC   1200000
#define E_CW   200000
#define CF     16
#define WF     8
#define H      128
#define OUTF   75

#define CAP_W  224          // bucket capacity per well (deg ~ Poisson(100))
#define WPB    4            // wells per block in k_head

#define CPB    256          // cells per dst-bin (bin = dst>>8)
#define NBIN   782          // ceil(200000/256)
#define NBLK_P 128          // partition blocks for hist/scatter
#define CHUNK  9375         // E_CC / NBLK_P (exact)

__device__ __forceinline__ float b2f(unsigned short u) {
    union { unsigned int i; float f; } v; v.i = ((unsigned int)u) << 16; return v.f;
}
__device__ __forceinline__ unsigned short f2b(float f) {
    union { float f; unsigned int i; } v; v.f = f;
    unsigned int i = v.i;
    return (unsigned short)((i + 0x7fffu + ((i >> 16) & 1u)) >> 16);  // RNE
}
__device__ __forceinline__ float lo16(unsigned int v) { return b2f((unsigned short)(v & 0xffffu)); }
__device__ __forceinline__ float hi16(unsigned int v) { return b2f((unsigned short)(v >> 16)); }
__device__ __forceinline__ float ldf(const void* p, int i, int bf) {
    return bf ? b2f(((const unsigned short*)p)[i]) : ((const float*)p)[i];
}

// ---- dtype sniff (bf16 vs f32), proven ----
__global__ __launch_bounds__(256) void k_sniff(const unsigned int* __restrict__ x, int* __restrict__ flag)
{
    __shared__ int cnt[256];
    int t = threadIdx.x;
    unsigned int d = x[t];
    unsigned int e = (d >> 7) & 0xffu;
    cnt[t] = (e >= 110u && e <= 135u) ? 1 : 0;
    __syncthreads();
    for (int o = 128; o > 0; o >>= 1) { if (t < o) cnt[t] += cnt[t + o]; __syncthreads(); }
    if (t == 0) flag[0] = (cnt[0] >= 192) ? 1 : 0;
}

// ---- stage-1 fused weights (proven) ----
__global__ __launch_bounds__(128) void k_precomp(const void* __restrict__ W_cell,
                                                 const void* __restrict__ b_cell,
                                                 const void* __restrict__ Wl,
                                                 const void* __restrict__ Wr,
                                                 const void* __restrict__ bl,
                                                 const int* __restrict__ flag,
                                                 float* __restrict__ G1, float* __restrict__ G2,
                                                 float* __restrict__ g1v, float* __restrict__ g2v)
{
    int f = threadIdx.x, b = blockIdx.x, bf = flag[0];
    if (b < 16) {
        float s1 = 0.f, s2 = 0.f;
        for (int j = 0; j < H; ++j) {
            float wc = ldf(W_cell, b * H + j, bf);
            s1 += wc * ldf(Wl, j * H + f, bf);
            s2 += wc * ldf(Wr, j * H + f, bf);
        }
        G1[b * H + f] = s1; G2[b * H + f] = s2;
    } else {
        float s1 = 0.f, s2 = 0.f;
        for (int j = 0; j < H; ++j) {
            float bc = ldf(b_cell, j, bf);
            s1 += bc * ldf(Wl, j * H + f, bf);
            s2 += bc * ldf(Wr, j * H + f, bf);
        }
        g1v[f] = s1; g2v[f] = s2 + ldf(bl, f, bf);
    }
}

// ---- stage-2 fused weights (folds SAGE-cw layer, proven) ----
__global__ __launch_bounds__(128) void k_precomp2(const float* __restrict__ G1, const float* __restrict__ G2,
                                                  const float* __restrict__ g1v, const float* __restrict__ g2v,
                                                  const void* __restrict__ Wl_cw,
                                                  const void* __restrict__ bl_cw,
                                                  const void* __restrict__ Wr_cw,
                                                  const void* __restrict__ W_well,
                                                  const void* __restrict__ b_well,
                                                  const int* __restrict__ flag,
                                                  float* __restrict__ A1, float* __restrict__ A2,
                                                  float* __restrict__ Bm,
                                                  float* __restrict__ a1, float* __restrict__ a2,
                                                  float* __restrict__ b0)
{
    int f = threadIdx.x, b = blockIdx.x, bf = flag[0];
    if (b < 16) {
        float s1 = 0.f, s2 = 0.f;
        for (int j = 0; j < H; ++j) {
            float wl = ldf(Wl_cw, j * H + f, bf);
            s1 += G1[b * H + j] * wl;
            s2 += G2[b * H + j] * wl;
        }
        A1[b * H + f] = s1; A2[b * H + f] = s2;
    } else if (b < 24) {
        int k = b - 16;
        float s = 0.f;
        for (int j = 0; j < H; ++j)
            s += ldf(W_well, k * H + j, bf) * ldf(Wr_cw, j * H + f, bf);
        Bm[k * H + f] = s;
    } else {
        float s1 = 0.f, s2 = 0.f, s3 = 0.f;
        for (int j = 0; j < H; ++j) {
            float wl = ldf(Wl_cw, j * H + f, bf);
            s1 += g1v[j] * wl;
            s2 += g2v[j] * wl;
            s3 += ldf(b_well, j, bf) * ldf(Wr_cw, j * H + f, bf);
        }
        a1[f] = s1; a2[f] = s2; b0[f] = s3 + ldf(bl_cw, f, bf);
    }
}

// ---- convert MLP weights to f32 (proven) ----
__global__ __launch_bounds__(256) void k_cvt(const void* __restrict__ Wm1, const void* __restrict__ Wm2,
                                             const void* __restrict__ bm1, const void* __restrict__ bm2,
                                             const int* __restrict__ flag,
                                             float* __restrict__ Wm1f, float* __restrict__ Wm2f,
                                             float* __restrict__ bm1f, float* __restrict__ bm2f)
{
    int i = blockIdx.x * 256 + threadIdx.x, bf = flag[0];
    if (i < H * H) Wm1f[i] = ldf(Wm1, i, bf);
    else if (i < H * H + H * OUTF) Wm2f[i - H * H] = ldf(Wm2, i - H * H, bf);
    else if (i < H * H + H * OUTF + H) bm1f[i - H * H - H * OUTF] = ldf(bm1, i - H * H - H * OUTF, bf);
    else if (i < H * H + H * OUTF + H + OUTF) bm2f[i - H * H - H * OUTF - H] = ldf(bm2, i - H * H - H * OUTF - H, bf);
}

// ---- fused: mark cells + well-bucket build ----
__global__ void k_markw(const int* __restrict__ ews, const int* __restrict__ ewd,
                        unsigned char* __restrict__ mark,
                        int* __restrict__ counts_w, int* __restrict__ buckets_w)
{
    int i = blockIdx.x * 256 + threadIdx.x;
    if (i < E_CW) {
        unsigned c = (unsigned)ews[i];
        if (c < N_CELL) mark[c] = 1;
        unsigned d = (unsigned)ewd[i];
        if (d < N_WELL) {
            int s = atomicAdd(&counts_w[d], 1);
            if (s < CAP_W) buckets_w[d * CAP_W + s] = ews[i];
        }
    }
}

// ---- pass 1: per-block LDS histogram over dst-bins, flush once per block ----
__global__ __launch_bounds__(256) void k_hist(const int* __restrict__ cc_dst,
                                              const unsigned char* __restrict__ mark,
                                              int* __restrict__ bin_cnt)
{
    __shared__ int hl[NBIN];
    int t = threadIdx.x;
    for (int i = t; i < NBIN; i += 256) hl[i] = 0;
    __syncthreads();
    int beg = blockIdx.x * CHUNK, end = beg + CHUNK; if (end > E_CC) end = E_CC;
    for (int e = beg + t; e < end; e += 256) {
        unsigned d = (unsigned)cc_dst[e];
        if (d < N_CELL && mark[d]) atomicAdd(&hl[d >> 8], 1);
    }
    __syncthreads();
    for (int i = t; i < NBIN; i += 256) if (hl[i]) atomicAdd(&bin_cnt[i], hl[i]);
}

// ---- scan bin counts -> offsets + cursors (single block) ----
__global__ __launch_bounds__(1024) void k_scanbins(const int* __restrict__ bin_cnt,
                                                   int* __restrict__ bin_off, int* __restrict__ bin_cur)
{
    __shared__ int sm[1024];
    int t = threadIdx.x;
    sm[t] = (t < NBIN) ? bin_cnt[t] : 0;
    __syncthreads();
    for (int o = 1; o < 1024; o <<= 1) {
        int u = (t >= o) ? sm[t - o] : 0;
        __syncthreads();
        sm[t] += u;
        __syncthreads();
    }
    if (t < NBIN) {
        int v = sm[t];
        bin_off[t + 1] = v;
        bin_cur[t] = v - bin_cnt[t];     // exclusive prefix
        if (t == 0) bin_off[0] = 0;
    }
}

// ---- pass 2: block-aggregated scatter into bins; payload = src | dloc<<18 ----
__global__ __launch_bounds__(256) void k_scatter(const int* __restrict__ cc_src,
                                                 const int* __restrict__ cc_dst,
                                                 const unsigned char* __restrict__ mark,
                                                 int* __restrict__ bin_cur,
                                                 unsigned int* __restrict__ binned)
{
    __shared__ int hl[NBIN];
    __shared__ int cur[NBIN];
    int t = threadIdx.x;
    for (int i = t; i < NBIN; i += 256) hl[i] = 0;
    __syncthreads();
    int beg = blockIdx.x * CHUNK, end = beg + CHUNK; if (end > E_CC) end = E_CC;
    for (int e = beg + t; e < end; e += 256) {
        unsigned d = (unsigned)cc_dst[e];
        if (d < N_CELL && mark[d]) atomicAdd(&hl[d >> 8], 1);
    }
    __syncthreads();
    for (int i = t; i < NBIN; i += 256)
        cur[i] = hl[i] ? atomicAdd(&bin_cur[i], hl[i]) : 0;   // one reservation per (block,bin)
    __syncthreads();
    for (int e = beg + t; e < end; e += 256) {
        unsigned d = (unsigned)cc_dst[e];
        if (d < N_CELL && mark[d]) {
            unsigned s = (unsigned)cc_src[e]; if (s >= N_CELL) s = 0;
            int slot = atomicAdd(&cur[d >> 8], 1);            // LDS rank
            if ((unsigned)slot < E_CC)
                binned[slot] = s | ((d & 255u) << 18);
        }
    }
}

// ---- per-bin aggregation: LDS f32 accumulate, coalesced y/deg writes ----
__global__ __launch_bounds__(256) void k_binagg(const void* __restrict__ xr,
                                                const int* __restrict__ flag,
                                                const int* __restrict__ bin_off,
                                                const unsigned int* __restrict__ binned,
                                                float* __restrict__ y, int* __restrict__ counts_c)
{
    __shared__ float yl[CPB * 16];     // 16 KB
    __shared__ int   dl[CPB];
    __shared__ float il[CPB];
    int b = blockIdx.x, t = threadIdx.x, bf = flag[0];
    for (int i = t; i < CPB * 16; i += 256) yl[i] = 0.f;
    if (t < CPB) dl[t] = 0;
    __syncthreads();
    int beg = bin_off[b], end = bin_off[b + 1];
    if (beg < 0) beg = 0;
    if (end > E_CC) end = E_CC;
    for (int e = beg + t; e < end; e += 256) {
        unsigned p = binned[e];
        unsigned s = p & 0x3FFFFu; if (s >= N_CELL) s = 0;
        int dloc = (p >> 18) & 255;
        atomicAdd(&dl[dloc], 1);
        float* yr = &yl[dloc * 16];
        if (bf) {
            uint4 a = ((const uint4*)xr)[(size_t)s * 2];
            uint4 bq = ((const uint4*)xr)[(size_t)s * 2 + 1];
            atomicAdd(&yr[0],  lo16(a.x));  atomicAdd(&yr[1],  hi16(a.x));
            atomicAdd(&yr[2],  lo16(a.y));  atomicAdd(&yr[3],  hi16(a.y));
            atomicAdd(&yr[4],  lo16(a.z));  atomicAdd(&yr[5],  hi16(a.z));
            atomicAdd(&yr[6],  lo16(a.w));  atomicAdd(&yr[7],  hi16(a.w));
            atomicAdd(&yr[8],  lo16(bq.x)); atomicAdd(&yr[9],  hi16(bq.x));
            atomicAdd(&yr[10], lo16(bq.y)); atomicAdd(&yr[11], hi16(bq.y));
            atomicAdd(&yr[12], lo16(bq.z)); atomicAdd(&yr[13], hi16(bq.z));
            atomicAdd(&yr[14], lo16(bq.w)); atomicAdd(&yr[15], hi16(bq.w));
        } else {
            const float4* pp = (const float4*)xr + (size_t)s * 4;
#pragma unroll
            for (int q = 0; q < 4; ++q) {
                float4 v = pp[q];
                atomicAdd(&yr[4 * q],     v.x); atomicAdd(&yr[4 * q + 1], v.y);
                atomicAdd(&yr[4 * q + 2], v.z); atomicAdd(&yr[4 * q + 3], v.w);
            }
        }
    }
    __syncthreads();
    if (t < CPB) {
        int d = dl[t];
        il[t] = (d > 0) ? (1.0f / (float)d) : 0.f;
        int c = b * CPB + t;
        if (c < N_CELL) counts_c[c] = d;
    }
    __syncthreads();
    size_t base = (size_t)b * CPB * 16;
    for (int i = t; i < CPB * 16; i += 256) {
        int cl = i >> 4;
        if (b * CPB + cl < N_CELL) y[base + i] = yl[i] * il[cl];
    }
}

// ---- per-well aggregation + folded SAGE-cw (proven) ----
__global__ __launch_bounds__(256) void k_wellagg(const void* __restrict__ xr,
                                                 const int* __restrict__ flag,
                                                 const float* __restrict__ y,
                                                 const int* __restrict__ counts_c,
                                                 const int* __restrict__ counts_w,
                                                 const int* __restrict__ buckets_w,
                                                 const void* __restrict__ wx,
                                                 const float* __restrict__ A1, const float* __restrict__ A2,
                                                 const float* __restrict__ Bm,
                                                 const float* __restrict__ a1, const float* __restrict__ a2,
                                                 const float* __restrict__ b0,
                                                 float* __restrict__ Z)
{
    __shared__ float sP[16], sR[16], sq[1];
    int w = blockIdx.x, t = threadIdx.x, bf = flag[0];
    int g = t >> 3, jl = t & 7;
    if (t < 16) { sP[t] = 0.f; sR[t] = 0.f; }
    if (t == 16) sq[0] = 0.f;
    __syncthreads();

    int cntw = counts_w[w]; if (cntw < 0) cntw = 0;
    int lim = (cntw < CAP_W) ? cntw : CAP_W;

    float p0 = 0.f, p1 = 0.f, r0 = 0.f, r1 = 0.f, qn = 0.f;
    const unsigned int* x32 = (const unsigned int*)xr;
    const float* xf = (const float*)xr;

    for (int e = g; e < lim; e += 32) {
        unsigned c = (unsigned)buckets_w[w * CAP_W + e]; if (c >= N_CELL) c = 0;
        float2 yv = ((const float2*)y)[(size_t)c * 8 + jl];
        p0 += yv.x; p1 += yv.y;
        if (bf) {
            unsigned int u = x32[(size_t)c * 8 + jl];
            r0 += lo16(u); r1 += hi16(u);
        } else {
            r0 += xf[(size_t)c * 16 + 2 * jl];
            r1 += xf[(size_t)c * 16 + 2 * jl + 1];
        }
        if (jl == 0) qn += (counts_c[c] > 0) ? 1.0f : 0.0f;
    }
    atomicAdd(&sP[2 * jl], p0);
    atomicAdd(&sP[2 * jl + 1], p1);
    atomicAdd(&sR[2 * jl], r0);
    atomicAdd(&sR[2 * jl + 1], r1);
    if (jl == 0 && qn != 0.f) atomicAdd(&sq[0], qn);
    __syncthreads();

    int f = t;
    if (f < H) {
        float inv = (cntw > 0) ? (1.0f / (float)cntw) : 0.0f;
        float mask = (cntw > 0) ? 1.0f : 0.0f;
        float wh = (sq[0] * inv) * a1[f] + a2[f];
#pragma unroll
        for (int k = 0; k < 16; ++k)
            wh += (sP[k] * inv) * A1[k * H + f] + (sR[k] * inv) * A2[k * H + f];
        wh *= mask;
        wh += b0[f];
#pragma unroll
        for (int k = 0; k < WF; ++k)
            wh += ldf(wx, w * WF + k, bf) * Bm[k * H + f];
        Z[(size_t)w * H + f] = wh;
    }
}

// ---- batched MLP head (proven) ----
__global__ __launch_bounds__(128) void k_head(const float* __restrict__ Z,
                                              const float* __restrict__ Wm1f, const float* __restrict__ Wm2f,
                                              const float* __restrict__ bm1f, const float* __restrict__ bm2f,
                                              const int* __restrict__ flag,
                                              void* __restrict__ outp)
{
    __shared__ float sz[WPB][H], sh[WPB][H];
    int w0 = blockIdx.x * WPB, t = threadIdx.x, bf = flag[0];
    float4 zv = ((const float4*)(Z + (size_t)w0 * H))[t];
    ((float4*)&sz[0][0])[t] = zv;
    __syncthreads();

    float acc[WPB];
#pragma unroll
    for (int i = 0; i < WPB; ++i) acc[i] = bm1f[t];
    for (int k = 0; k < H; ++k) {
        float wm = Wm1f[k * H + t];
#pragma unroll
        for (int i = 0; i < WPB; ++i) acc[i] += sz[i][k] * wm;
    }
#pragma unroll
    for (int i = 0; i < WPB; ++i) sh[i][t] = fmaxf(acc[i], 0.f);
    __syncthreads();

    if (t < OUTF) {
        float o[WPB];
#pragma unroll
        for (int i = 0; i < WPB; ++i) o[i] = bm2f[t];
        for (int k = 0; k < H; ++k) {
            float wm = Wm2f[k * OUTF + t];
#pragma unroll
            for (int i = 0; i < WPB; ++i) o[i] += sh[i][k] * wm;
        }
        if (bf) {
#pragma unroll
            for (int i = 0; i < WPB; ++i)
                ((unsigned short*)outp)[(size_t)(w0 + i) * OUTF + t] = f2b(o[i]);
        } else {
#pragma unroll
            for (int i = 0; i < WPB; ++i)
                ((float*)outp)[(size_t)(w0 + i) * OUTF + t] = o[i];
        }
    }
}

extern "C" void kernel_launch(void* const* d_in, const int* in_sizes, int n_in,
                              void* d_out, int out_size, void* d_ws, size_t ws_size,
                              hipStream_t stream)
{
    const void* cell_x = d_in[0];
    const void* well_x = d_in[1];
    const int* eic = (const int*)d_in[2];
    const int* ews = (const int*)d_in[3];
    const int* ewd = (const int*)d_in[4];
    const void* W_cell = d_in[5];
    const void* b_cell = d_in[6];
    const void* W_well = d_in[7];
    const void* b_well = d_in[8];
    const void* Wl_cc = d_in[9];
    const void* bl_cc = d_in[10];
    const void* Wr_cc = d_in[11];
    const void* Wl_cw = d_in[12];
    const void* bl_cw = d_in[13];
    const void* Wr_cw = d_in[14];
    const void* W_m1 = d_in[15];
    const void* b_m1 = d_in[16];
    const void* W_m2 = d_in[17];
    const void* b_m2 = d_in[18];
    (void)in_sizes; (void)n_in; (void)out_size; (void)ws_size;

    const int* cc_src = eic;
    const int* cc_dst = eic + E_CC;

    char* wsp = (char*)d_ws;
    size_t off = 0;
    auto carve = [&](size_t bytes) -> char* {
        char* p = wsp + off;
        off = (off + bytes + 255) & ~(size_t)255;
        return p;
    };

    // small fused-weight buffers
    float* G1   = (float*)carve(16 * H * 4);
    float* G2   = (float*)carve(16 * H * 4);
    float* g1v  = (float*)carve(H * 4);
    float* g2v  = (float*)carve(H * 4);
    float* A1   = (float*)carve(16 * H * 4);
    float* A2   = (float*)carve(16 * H * 4);
    float* Bm   = (float*)carve(WF * H * 4);
    float* a1   = (float*)carve(H * 4);
    float* a2   = (float*)carve(H * 4);
    float* b0   = (float*)carve(H * 4);
    float* Wm1f = (float*)carve(H * H * 4);
    float* Wm2f = (float*)carve(H * OUTF * 4);
    float* bm1f = (float*)carve(H * 4);
    float* bm2f = (float*)carve(OUTF * 4);
    int*   flag = (int*)carve(256);
    // zero region (one memset): counts + mark + bin_cnt
    size_t zero_beg = off;
    int*   counts   = (int*)carve((size_t)(N_CELL + N_WELL) * 4);
    int*   counts_c = counts;
    int*   counts_w = counts + N_CELL;
    unsigned char* mark = (unsigned char*)carve((size_t)N_CELL);
    int*   bin_cnt = (int*)carve((size_t)(NBIN + 2) * 4);
    size_t zero_end = off;
    // big buffers (~21.7 MB total; ws proven >= ~35 MB in R5/R6)
    int*   bin_off  = (int*)carve((size_t)(NBIN + 2) * 4);
    int*   bin_cur  = (int*)carve((size_t)(NBIN + 2) * 4);
    unsigned int* binned = (unsigned int*)carve((size_t)E_CC * 4);   // 4.8 MB
    int*   buckets_w = (int*)carve((size_t)N_WELL * CAP_W * 4);      // 1.8 MB
    float* y         = (float*)carve((size_t)NBIN * CPB * 16 * 4);   // 12.8 MB
    float* Z         = (float*)carve((size_t)N_WELL * H * 4);        // 1 MB

    k_sniff<<<1, 256, 0, stream>>>((const unsigned int*)cell_x, flag);
    hipMemsetAsync((char*)d_ws + zero_beg, 0, zero_end - zero_beg, stream);
    k_precomp<<<17, 128, 0, stream>>>(W_cell, b_cell, Wl_cc, Wr_cc, bl_cc, flag, G1, G2, g1v, g2v);
    k_precomp2<<<25, 128, 0, stream>>>(G1, G2, g1v, g2v, Wl_cw, bl_cw, Wr_cw, W_well, b_well, flag,
                                       A1, A2, Bm, a1, a2, b0);
    k_cvt<<<(H * H + H * OUTF + H + OUTF + 255) / 256, 256, 0, stream>>>(W_m1, W_m2, b_m1, b_m2, flag,
                                                                         Wm1f, Wm2f, bm1f, bm2f);
    k_markw<<<(E_CW + 255) / 256, 256, 0, stream>>>(ews, ewd, mark, counts_w, buckets_w);
    k_hist<<<NBLK_P, 256, 0, stream>>>(cc_dst, mark, bin_cnt);
    k_scanbins<<<1, 1024, 0, stream>>>(bin_cnt, bin_off, bin_cur);
    k_scatter<<<NBLK_P, 256, 0, stream>>>(cc_src, cc_dst, mark, bin_cur, binned);
    k_binagg<<<NBIN, 256, 0, stream>>>(cell_x, flag, bin_off, binned, y, counts_c);
    k_wellagg<<<N_WELL, 256, 0, stream>>>(cell_x, flag, y, counts_c, counts_w, buckets_w,
                                          well_x, A1, A2, Bm, a1, a2, b0, Z);
    k_head<<<N_WELL / WPB, 128, 0, stream>>>(Z, Wm1f, Wm2f, bm1f, bm2f, flag, d_out);
}

// Round 9
// 295.429 us; speedup vs baseline: 1.2444x; 1.2444x over previous
//
#include <hip/hip_runtime.h>

#define N_CELL 200000
#define N_WELL 2000
#define E_CC   1200000
#define E_CW   200000
#define CF     16
#define WF     8
#define H      128
#define OUTF   75

#define CAP_C  16           // bucket row = exactly one 64B line; overflow -> side list
#define CAP_W  224          // bucket capacity per well (deg ~ Poisson(100))
#define OVF_CAP 16384
#define WPB    4            // wells per block in k_head

#define BLD_T  307200       // k_build stride (1200 blocks * 256); 4 edges/thread
#define MKW_T  50176        // k_markw stride (196 blocks * 256); 4 edges/thread

__device__ __forceinline__ float b2f(unsigned short u) {
    union { unsigned int i; float f; } v; v.i = ((unsigned int)u) << 16; return v.f;
}
__device__ __forceinline__ unsigned short f2b(float f) {
    union { float f; unsigned int i; } v; v.f = f;
    unsigned int i = v.i;
    return (unsigned short)((i + 0x7fffu + ((i >> 16) & 1u)) >> 16);  // RNE
}
__device__ __forceinline__ float lo16(unsigned int v) { return b2f((unsigned short)(v & 0xffffu)); }
__device__ __forceinline__ float hi16(unsigned int v) { return b2f((unsigned short)(v >> 16)); }
__device__ __forceinline__ float ldf(const void* p, int i, int bf) {
    return bf ? b2f(((const unsigned short*)p)[i]) : ((const float*)p)[i];
}

// ---- dtype sniff (bf16 vs f32), proven ----
__global__ __launch_bounds__(256) void k_sniff(const unsigned int* __restrict__ x, int* __restrict__ flag)
{
    __shared__ int cnt[256];
    int t = threadIdx.x;
    unsigned int d = x[t];
    unsigned int e = (d >> 7) & 0xffu;
    cnt[t] = (e >= 110u && e <= 135u) ? 1 : 0;
    __syncthreads();
    for (int o = 128; o > 0; o >>= 1) { if (t < o) cnt[t] += cnt[t + o]; __syncthreads(); }
    if (t == 0) flag[0] = (cnt[0] >= 192) ? 1 : 0;
}

// ---- stage-1 fused weights (proven) ----
__global__ __launch_bounds__(128) void k_precomp(const void* __restrict__ W_cell,
                                                 const void* __restrict__ b_cell,
                                                 const void* __restrict__ Wl,
                                                 const void* __restrict__ Wr,
                                                 const void* __restrict__ bl,
                                                 const int* __restrict__ flag,
                                                 float* __restrict__ G1, float* __restrict__ G2,
                                                 float* __restrict__ g1v, float* __restrict__ g2v)
{
    int f = threadIdx.x, b = blockIdx.x, bf = flag[0];
    if (b < 16) {
        float s1 = 0.f, s2 = 0.f;
        for (int j = 0; j < H; ++j) {
            float wc = ldf(W_cell, b * H + j, bf);
            s1 += wc * ldf(Wl, j * H + f, bf);
            s2 += wc * ldf(Wr, j * H + f, bf);
        }
        G1[b * H + f] = s1; G2[b * H + f] = s2;
    } else {
        float s1 = 0.f, s2 = 0.f;
        for (int j = 0; j < H; ++j) {
            float bc = ldf(b_cell, j, bf);
            s1 += bc * ldf(Wl, j * H + f, bf);
            s2 += bc * ldf(Wr, j * H + f, bf);
        }
        g1v[f] = s1; g2v[f] = s2 + ldf(bl, f, bf);
    }
}

// ---- stage-2 fused weights + MLP weight conversion (fused, blocks 25..229) ----
__global__ __launch_bounds__(128) void k_precomp2(const float* __restrict__ G1, const float* __restrict__ G2,
                                                  const float* __restrict__ g1v, const float* __restrict__ g2v,
                                                  const void* __restrict__ Wl_cw,
                                                  const void* __restrict__ bl_cw,
                                                  const void* __restrict__ Wr_cw,
                                                  const void* __restrict__ W_well,
                                                  const void* __restrict__ b_well,
                                                  const void* __restrict__ Wm1, const void* __restrict__ Wm2,
                                                  const void* __restrict__ bm1, const void* __restrict__ bm2,
                                                  const int* __restrict__ flag,
                                                  float* __restrict__ A1, float* __restrict__ A2,
                                                  float* __restrict__ Bm,
                                                  float* __restrict__ a1, float* __restrict__ a2,
                                                  float* __restrict__ b0,
                                                  float* __restrict__ Wm1f, float* __restrict__ Wm2f,
                                                  float* __restrict__ bm1f, float* __restrict__ bm2f)
{
    int f = threadIdx.x, b = blockIdx.x, bf = flag[0];
    if (b < 16) {
        float s1 = 0.f, s2 = 0.f;
        for (int j = 0; j < H; ++j) {
            float wl = ldf(Wl_cw, j * H + f, bf);
            s1 += G1[b * H + j] * wl;
            s2 += G2[b * H + j] * wl;
        }
        A1[b * H + f] = s1; A2[b * H + f] = s2;
    } else if (b < 24) {
        int k = b - 16;
        float s = 0.f;
        for (int j = 0; j < H; ++j)
            s += ldf(W_well, k * H + j, bf) * ldf(Wr_cw, j * H + f, bf);
        Bm[k * H + f] = s;
    } else if (b == 24) {
        float s1 = 0.f, s2 = 0.f, s3 = 0.f;
        for (int j = 0; j < H; ++j) {
            float wl = ldf(Wl_cw, j * H + f, bf);
            s1 += g1v[j] * wl;
            s2 += g2v[j] * wl;
            s3 += ldf(b_well, j, bf) * ldf(Wr_cw, j * H + f, bf);
        }
        a1[f] = s1; a2[f] = s2; b0[f] = s3 + ldf(bl_cw, f, bf);
    } else {
        int i = (b - 25) * 128 + f;
        if (i < H * H) Wm1f[i] = ldf(Wm1, i, bf);
        else if (i < H * H + H * OUTF) Wm2f[i - H * H] = ldf(Wm2, i - H * H, bf);
        else if (i < H * H + H * OUTF + H) bm1f[i - H * H - H * OUTF] = ldf(bm1, i - H * H - H * OUTF, bf);
        else if (i < H * H + H * OUTF + H + OUTF) bm2f[i - H * H - H * OUTF - H] = ldf(bm2, i - H * H - H * OUTF - H, bf);
    }
}

// ---- fused: mark cells + well-bucket build; 4 independent edges per thread ----
__global__ __launch_bounds__(256) void k_markw(const int* __restrict__ ews, const int* __restrict__ ewd,
                                               unsigned char* __restrict__ mark,
                                               int* __restrict__ counts_w, int* __restrict__ buckets_w)
{
    int i = blockIdx.x * 256 + threadIdx.x;
#pragma unroll
    for (int u = 0; u < 4; ++u) {
        int e = i + u * MKW_T;
        if (e < E_CW) {
            unsigned c = (unsigned)ews[e];
            if (c < N_CELL) mark[c] = 1;
            unsigned d = (unsigned)ewd[e];
            if (d < N_WELL) {
                int s = atomicAdd(&counts_w[d], 1);
                if (s < CAP_W) buckets_w[d * CAP_W + s] = (int)c;
            }
        }
    }
}

// ---- bucket CSR build (cc edges, mark-filtered); 4 independent edge-chains per thread ----
__global__ __launch_bounds__(256) void k_build(const int* __restrict__ cc_src, const int* __restrict__ cc_dst,
                                               const unsigned char* __restrict__ mark,
                                               int* __restrict__ counts_c,
                                               int* __restrict__ buckets_c,
                                               int* __restrict__ ovf_cnt, int2* __restrict__ ovf)
{
    int i = blockIdx.x * 256 + threadIdx.x;
    int e0 = i, e1 = i + BLD_T, e2 = i + 2 * BLD_T, e3 = i + 3 * BLD_T;
    // 4 independent chains: loads of dst
    unsigned d0 = (e0 < E_CC) ? (unsigned)cc_dst[e0] : 0xFFFFFFFFu;
    unsigned d1 = (e1 < E_CC) ? (unsigned)cc_dst[e1] : 0xFFFFFFFFu;
    unsigned d2 = (e2 < E_CC) ? (unsigned)cc_dst[e2] : 0xFFFFFFFFu;
    unsigned d3 = (e3 < E_CC) ? (unsigned)cc_dst[e3] : 0xFFFFFFFFu;
    // mark probes (independent)
    bool m0 = (d0 < N_CELL) && mark[d0];
    bool m1 = (d1 < N_CELL) && mark[d1];
    bool m2 = (d2 < N_CELL) && mark[d2];
    bool m3 = (d3 < N_CELL) && mark[d3];
    // src loads (independent, coalesced)
    int s0 = m0 ? cc_src[e0] : 0;
    int s1 = m1 ? cc_src[e1] : 0;
    int s2 = m2 ? cc_src[e2] : 0;
    int s3 = m3 ? cc_src[e3] : 0;
    // atomics + stores (4 independent chains)
    if (m0) {
        int p = atomicAdd(&counts_c[d0], 1);
        if (p < CAP_C) buckets_c[d0 * CAP_C + p] = s0;
        else { int q = atomicAdd(ovf_cnt, 1); if (q < OVF_CAP) { ovf[q].x = (int)d0; ovf[q].y = s0; } }
    }
    if (m1) {
        int p = atomicAdd(&counts_c[d1], 1);
        if (p < CAP_C) buckets_c[d1 * CAP_C + p] = s1;
        else { int q = atomicAdd(ovf_cnt, 1); if (q < OVF_CAP) { ovf[q].x = (int)d1; ovf[q].y = s1; } }
    }
    if (m2) {
        int p = atomicAdd(&counts_c[d2], 1);
        if (p < CAP_C) buckets_c[d2 * CAP_C + p] = s2;
        else { int q = atomicAdd(ovf_cnt, 1); if (q < OVF_CAP) { ovf[q].x = (int)d2; ovf[q].y = s2; } }
    }
    if (m3) {
        int p = atomicAdd(&counts_c[d3], 1);
        if (p < CAP_C) buckets_c[d3 * CAP_C + p] = s3;
        else { int q = atomicAdd(ovf_cnt, 1); if (q < OVF_CAP) { ovf[q].x = (int)d3; ovf[q].y = s3; } }
    }
}

// ---- phase A: y[c][16] = mask_c * mean_nbr(x), marked cells only; 2 independent gather chains ----
__global__ __launch_bounds__(256) void k_aggA(const void* __restrict__ xr,
                                              const int* __restrict__ flag,
                                              const unsigned char* __restrict__ mark,
                                              const int* __restrict__ counts_c,
                                              const int* __restrict__ buckets_c,
                                              float* __restrict__ y)
{
    int gid = (blockIdx.x * 256 + threadIdx.x) >> 3;
    int jl = threadIdx.x & 7;
    if (gid >= N_CELL) return;
    if (!mark[gid]) return;
    int bf = flag[0];
    int cnt = counts_c[gid]; if (cnt < 0) cnt = 0;
    int lim = (cnt < CAP_C) ? cnt : CAP_C;
    float acc[16];
#pragma unroll
    for (int k = 0; k < 16; ++k) acc[k] = 0.f;

    int j0 = jl, j1 = jl + 8;
    unsigned s0 = (j0 < lim) ? (unsigned)buckets_c[gid * CAP_C + j0] : 0xFFFFFFFFu;
    unsigned s1 = (j1 < lim) ? (unsigned)buckets_c[gid * CAP_C + j1] : 0xFFFFFFFFu;
    if (s0 >= N_CELL) s0 = 0xFFFFFFFFu;
    if (s1 >= N_CELL) s1 = 0xFFFFFFFFu;

    if (bf) {
        uint4 a0, b0q, a1, b1q;
        bool v0 = (s0 != 0xFFFFFFFFu), v1 = (s1 != 0xFFFFFFFFu);
        if (v0) { a0 = ((const uint4*)xr)[(size_t)s0 * 2]; b0q = ((const uint4*)xr)[(size_t)s0 * 2 + 1]; }
        if (v1) { a1 = ((const uint4*)xr)[(size_t)s1 * 2]; b1q = ((const uint4*)xr)[(size_t)s1 * 2 + 1]; }
        if (v0) {
            acc[0] += lo16(a0.x);  acc[1] += hi16(a0.x);
            acc[2] += lo16(a0.y);  acc[3] += hi16(a0.y);
            acc[4] += lo16(a0.z);  acc[5] += hi16(a0.z);
            acc[6] += lo16(a0.w);  acc[7] += hi16(a0.w);
            acc[8] += lo16(b0q.x); acc[9] += hi16(b0q.x);
            acc[10] += lo16(b0q.y); acc[11] += hi16(b0q.y);
            acc[12] += lo16(b0q.z); acc[13] += hi16(b0q.z);
            acc[14] += lo16(b0q.w); acc[15] += hi16(b0q.w);
        }
        if (v1) {
            acc[0] += lo16(a1.x);  acc[1] += hi16(a1.x);
            acc[2] += lo16(a1.y);  acc[3] += hi16(a1.y);
            acc[4] += lo16(a1.z);  acc[5] += hi16(a1.z);
            acc[6] += lo16(a1.w);  acc[7] += hi16(a1.w);
            acc[8] += lo16(b1q.x); acc[9] += hi16(b1q.x);
            acc[10] += lo16(b1q.y); acc[11] += hi16(b1q.y);
            acc[12] += lo16(b1q.z); acc[13] += hi16(b1q.z);
            acc[14] += lo16(b1q.w); acc[15] += hi16(b1q.w);
        }
    } else {
        if (s0 != 0xFFFFFFFFu) {
            const float4* p = (const float4*)xr + (size_t)s0 * 4;
#pragma unroll
            for (int q = 0; q < 4; ++q) {
                float4 v = p[q];
                acc[4 * q] += v.x; acc[4 * q + 1] += v.y; acc[4 * q + 2] += v.z; acc[4 * q + 3] += v.w;
            }
        }
        if (s1 != 0xFFFFFFFFu) {
            const float4* p = (const float4*)xr + (size_t)s1 * 4;
#pragma unroll
            for (int q = 0; q < 4; ++q) {
                float4 v = p[q];
                acc[4 * q] += v.x; acc[4 * q + 1] += v.y; acc[4 * q + 2] += v.z; acc[4 * q + 3] += v.w;
            }
        }
    }
#pragma unroll
    for (int m = 1; m < 8; m <<= 1) {
#pragma unroll
        for (int k = 0; k < 16; ++k) acc[k] += __shfl_xor(acc[k], m, 64);
    }
    float sc = (cnt > 0) ? (1.0f / (float)cnt) : 0.0f;
    float2 st; st.x = acc[2 * jl] * sc; st.y = acc[2 * jl + 1] * sc;
    ((float2*)y)[(size_t)gid * 8 + jl] = st;
}

// ---- fold overflow edges (deg>CAP_C) into y ----
__global__ __launch_bounds__(256) void k_ovf(const void* __restrict__ xr,
                                             const int* __restrict__ flag,
                                             const int* __restrict__ ovf_cnt,
                                             const int2* __restrict__ ovf,
                                             const int* __restrict__ counts_c,
                                             float* __restrict__ y)
{
    int gid = (blockIdx.x * 256 + threadIdx.x) >> 3;
    int jl = threadIdx.x & 7;
    int n = ovf_cnt[0]; if (n > OVF_CAP) n = OVF_CAP;
    if (gid >= n) return;
    int bf = flag[0];
    unsigned d = (unsigned)ovf[gid].x; if (d >= N_CELL) d = 0;
    unsigned s = (unsigned)ovf[gid].y; if (s >= N_CELL) s = 0;
    int cnt = counts_c[d];
    float inv = (cnt > 0) ? (1.0f / (float)cnt) : 0.0f;
    float v0, v1;
    if (bf) {
        unsigned int u = ((const unsigned int*)xr)[(size_t)s * 8 + jl];
        v0 = lo16(u); v1 = hi16(u);
    } else {
        v0 = ((const float*)xr)[(size_t)s * 16 + 2 * jl];
        v1 = ((const float*)xr)[(size_t)s * 16 + 2 * jl + 1];
    }
    atomicAdd(&y[(size_t)d * 16 + 2 * jl], v0 * inv);
    atomicAdd(&y[(size_t)d * 16 + 2 * jl + 1], v1 * inv);
}

// ---- per-well aggregation + folded SAGE-cw (proven) ----
__global__ __launch_bounds__(256) void k_wellagg(const void* __restrict__ xr,
                                                 const int* __restrict__ flag,
                                                 const float* __restrict__ y,
                                                 const int* __restrict__ counts_c,
                                                 const int* __restrict__ counts_w,
                                                 const int* __restrict__ buckets_w,
                                                 const void* __restrict__ wx,
                                                 const float* __restrict__ A1, const float* __restrict__ A2,
                                                 const float* __restrict__ Bm,
                                                 const float* __restrict__ a1, const float* __restrict__ a2,
                                                 const float* __restrict__ b0,
                                                 float* __restrict__ Z)
{
    __shared__ float sP[16], sR[16], sq[1];
    int w = blockIdx.x, t = threadIdx.x, bf = flag[0];
    int g = t >> 3, jl = t & 7;
    if (t < 16) { sP[t] = 0.f; sR[t] = 0.f; }
    if (t == 16) sq[0] = 0.f;
    __syncthreads();

    int cntw = counts_w[w]; if (cntw < 0) cntw = 0;
    int lim = (cntw < CAP_W) ? cntw : CAP_W;

    float p0 = 0.f, p1 = 0.f, r0 = 0.f, r1 = 0.f, qn = 0.f;
    const unsigned int* x32 = (const unsigned int*)xr;
    const float* xf = (const float*)xr;

    for (int e = g; e < lim; e += 32) {
        unsigned c = (unsigned)buckets_w[w * CAP_W + e]; if (c >= N_CELL) c = 0;
        float2 yv = ((const float2*)y)[(size_t)c * 8 + jl];
        p0 += yv.x; p1 += yv.y;
        if (bf) {
            unsigned int u = x32[(size_t)c * 8 + jl];
            r0 += lo16(u); r1 += hi16(u);
        } else {
            r0 += xf[(size_t)c * 16 + 2 * jl];
            r1 += xf[(size_t)c * 16 + 2 * jl + 1];
        }
        if (jl == 0) qn += (counts_c[c] > 0) ? 1.0f : 0.0f;
    }
    atomicAdd(&sP[2 * jl], p0);
    atomicAdd(&sP[2 * jl + 1], p1);
    atomicAdd(&sR[2 * jl], r0);
    atomicAdd(&sR[2 * jl + 1], r1);
    if (jl == 0 && qn != 0.f) atomicAdd(&sq[0], qn);
    __syncthreads();

    int f = t;
    if (f < H) {
        float inv = (cntw > 0) ? (1.0f / (float)cntw) : 0.0f;
        float mask = (cntw > 0) ? 1.0f : 0.0f;
        float wh = (sq[0] * inv) * a1[f] + a2[f];
#pragma unroll
        for (int k = 0; k < 16; ++k)
            wh += (sP[k] * inv) * A1[k * H + f] + (sR[k] * inv) * A2[k * H + f];
        wh *= mask;
        wh += b0[f];
#pragma unroll
        for (int k = 0; k < WF; ++k)
            wh += ldf(wx, w * WF + k, bf) * Bm[k * H + f];
        Z[(size_t)w * H + f] = wh;
    }
}

// ---- batched MLP head (proven) ----
__global__ __launch_bounds__(128) void k_head(const float* __restrict__ Z,
                                              const float* __restrict__ Wm1f, const float* __restrict__ Wm2f,
                                              const float* __restrict__ bm1f, const float* __restrict__ bm2f,
                                              const int* __restrict__ flag,
                                              void* __restrict__ outp)
{
    __shared__ float sz[WPB][H], sh[WPB][H];
    int w0 = blockIdx.x * WPB, t = threadIdx.x, bf = flag[0];
    float4 zv = ((const float4*)(Z + (size_t)w0 * H))[t];
    ((float4*)&sz[0][0])[t] = zv;
    __syncthreads();

    float acc[WPB];
#pragma unroll
    for (int i = 0; i < WPB; ++i) acc[i] = bm1f[t];
    for (int k = 0; k < H; ++k) {
        float wm = Wm1f[k * H + t];
#pragma unroll
        for (int i = 0; i < WPB; ++i) acc[i] += sz[i][k] * wm;
    }
#pragma unroll
    for (int i = 0; i < WPB; ++i) sh[i][t] = fmaxf(acc[i], 0.f);
    __syncthreads();

    if (t < OUTF) {
        float o[WPB];
#pragma unroll
        for (int i = 0; i < WPB; ++i) o[i] = bm2f[t];
        for (int k = 0; k < H; ++k) {
            float wm = Wm2f[k * OUTF + t];
#pragma unroll
            for (int i = 0; i < WPB; ++i) o[i] += sh[i][k] * wm;
        }
        if (bf) {
#pragma unroll
            for (int i = 0; i < WPB; ++i)
                ((unsigned short*)outp)[(size_t)(w0 + i) * OUTF + t] = f2b(o[i]);
        } else {
#pragma unroll
            for (int i = 0; i < WPB; ++i)
                ((float*)outp)[(size_t)(w0 + i) * OUTF + t] = o[i];
        }
    }
}

extern "C" void kernel_launch(void* const* d_in, const int* in_sizes, int n_in,
                              void* d_out, int out_size, void* d_ws, size_t ws_size,
                              hipStream_t stream)
{
    const void* cell_x = d_in[0];
    const void* well_x = d_in[1];
    const int* eic = (const int*)d_in[2];
    const int* ews = (const int*)d_in[3];
    const int* ewd = (const int*)d_in[4];
    const void* W_cell = d_in[5];
    const void* b_cell = d_in[6];
    const void* W_well = d_in[7];
    const void* b_well = d_in[8];
    const void* Wl_cc = d_in[9];
    const void* bl_cc = d_in[10];
    const void* Wr_cc = d_in[11];
    const void* Wl_cw = d_in[12];
    const void* bl_cw = d_in[13];
    const void* Wr_cw = d_in[14];
    const void* W_m1 = d_in[15];
    const void* b_m1 = d_in[16];
    const void* W_m2 = d_in[17];
    const void* b_m2 = d_in[18];
    (void)in_sizes; (void)n_in; (void)out_size; (void)ws_size;

    const int* cc_src = eic;
    const int* cc_dst = eic + E_CC;

    char* wsp = (char*)d_ws;
    size_t off = 0;
    auto carve = [&](size_t bytes) -> char* {
        char* p = wsp + off;
        off = (off + bytes + 255) & ~(size_t)255;
        return p;
    };

    // small fused-weight buffers
    float* G1   = (float*)carve(16 * H * 4);
    float* G2   = (float*)carve(16 * H * 4);
    float* g1v  = (float*)carve(H * 4);
    float* g2v  = (float*)carve(H * 4);
    float* A1   = (float*)carve(16 * H * 4);
    float* A2   = (float*)carve(16 * H * 4);
    float* Bm   = (float*)carve(WF * H * 4);
    float* a1   = (float*)carve(H * 4);
    float* a2   = (float*)carve(H * 4);
    float* b0   = (float*)carve(H * 4);
    float* Wm1f = (float*)carve(H * H * 4);
    float* Wm2f = (float*)carve(H * OUTF * 4);
    float* bm1f = (float*)carve(H * 4);
    float* bm2f = (float*)carve(OUTF * 4);
    int*   flag = (int*)carve(256);
    // zero region (one memset): counts + mark + ovf_cnt
    size_t zero_beg = off;
    int*   counts   = (int*)carve((size_t)(N_CELL + N_WELL) * 4);
    int*   counts_c = counts;
    int*   counts_w = counts + N_CELL;
    unsigned char* mark = (unsigned char*)carve((size_t)N_CELL);
    int*   ovf_cnt  = (int*)carve(256);
    size_t zero_end = off;
    // big buffers (~29.5 MB; ws proven >= ~35 MB in R5/R6)
    int*   buckets_c = (int*)carve((size_t)N_CELL * CAP_C * 4);   // 12.8 MB
    int*   buckets_w = (int*)carve((size_t)N_WELL * CAP_W * 4);   // 1.8 MB
    float* y         = (float*)carve((size_t)N_CELL * 16 * 4);    // 12.8 MB
    int2*  ovf       = (int2*)carve((size_t)OVF_CAP * 8);         // 128 KB
    float* Z         = (float*)carve((size_t)N_WELL * H * 4);     // 1 MB

    k_sniff<<<1, 256, 0, stream>>>((const unsigned int*)cell_x, flag);
    hipMemsetAsync((char*)d_ws + zero_beg, 0, zero_end - zero_beg, stream);
    k_precomp<<<17, 128, 0, stream>>>(W_cell, b_cell, Wl_cc, Wr_cc, bl_cc, flag, G1, G2, g1v, g2v);
    k_precomp2<<<230, 128, 0, stream>>>(G1, G2, g1v, g2v, Wl_cw, bl_cw, Wr_cw, W_well, b_well,
                                        W_m1, W_m2, b_m1, b_m2, flag,
                                        A1, A2, Bm, a1, a2, b0, Wm1f, Wm2f, bm1f, bm2f);
    k_markw<<<MKW_T / 256, 256, 0, stream>>>(ews, ewd, mark, counts_w, buckets_w);
    k_build<<<BLD_T / 256, 256, 0, stream>>>(cc_src, cc_dst, mark, counts_c, buckets_c, ovf_cnt, ovf);
    k_aggA<<<(N_CELL * 8 + 255) / 256, 256, 0, stream>>>(cell_x, flag, mark, counts_c, buckets_c, y);
    k_ovf<<<(OVF_CAP * 8 + 255) / 256, 256, 0, stream>>>(cell_x, flag, ovf_cnt, ovf, counts_c, y);
    k_wellagg<<<N_WELL, 256, 0, stream>>>(cell_x, flag, y, counts_c, counts_w, buckets_w,
                                          well_x, A1, A2, Bm, a1, a2, b0, Z);
    k_head<<<N_WELL / WPB, 128, 0, stream>>>(Z, Wm1f, Wm2f, bm1f, bm2f, flag, d_out);
}

// Round 10
// 289.673 us; speedup vs baseline: 1.2691x; 1.0199x over previous
//
#include <hip/hip_runtime.h>

#define N_CELL 200000
#define N_WELL 2000
#define E_CC   1200000
#define E_CW   200000
#define CF     16
#define WF     8
#define H      128
#define OUTF   75

#define CAP_C  16           // bucket row = exactly one 64B line; overflow -> side list
#define CAP_W  224          // bucket capacity per well (deg ~ Poisson(100))
#define OVF_CAP 16384
#define WPB    4            // wells per block in k_head

#define BLD_T  307200       // k_build stride (1200 blocks * 256); 4 edges/thread

__device__ __forceinline__ float b2f(unsigned short u) {
    union { unsigned int i; float f; } v; v.i = ((unsigned int)u) << 16; return v.f;
}
__device__ __forceinline__ unsigned short f2b(float f) {
    union { float f; unsigned int i; } v; v.f = f;
    unsigned int i = v.i;
    return (unsigned short)((i + 0x7fffu + ((i >> 16) & 1u)) >> 16);  // RNE
}
__device__ __forceinline__ float lo16(unsigned int v) { return b2f((unsigned short)(v & 0xffffu)); }
__device__ __forceinline__ float hi16(unsigned int v) { return b2f((unsigned short)(v >> 16)); }
__device__ __forceinline__ float ldf(const void* p, int i, int bf) {
    return bf ? b2f(((const unsigned short*)p)[i]) : ((const float*)p)[i];
}

// per-block inline dtype sniff (128 threads): no cross-block dependency
__device__ __forceinline__ int sniff128(const unsigned int* __restrict__ x)
{
    __shared__ int cnt[128];
    int t = threadIdx.x;
    unsigned a = x[t], b = x[t + 128];
    unsigned ea = (a >> 7) & 0xffu, eb = (b >> 7) & 0xffu;
    cnt[t] = ((ea >= 110u && ea <= 135u) ? 1 : 0) + ((eb >= 110u && eb <= 135u) ? 1 : 0);
    __syncthreads();
    for (int o = 64; o > 0; o >>= 1) { if (t < o) cnt[t] += cnt[t + o]; __syncthreads(); }
    int r = (cnt[0] >= 192) ? 1 : 0;
    __syncthreads();
    return r;
}

// ---- setup1: blocks 0..16 stage-1 precomp (inline sniff); block 17 flag store; blocks 18..81 zeroing ----
__global__ __launch_bounds__(128) void k_setup1(const unsigned int* __restrict__ x256,
                                                const void* __restrict__ W_cell,
                                                const void* __restrict__ b_cell,
                                                const void* __restrict__ Wl,
                                                const void* __restrict__ Wr,
                                                const void* __restrict__ bl,
                                                float* __restrict__ G1, float* __restrict__ G2,
                                                float* __restrict__ g1v, float* __restrict__ g2v,
                                                int* __restrict__ flag,
                                                unsigned int* __restrict__ zero_p, int zero_dw)
{
    int f = threadIdx.x, b = blockIdx.x;
    if (b < 16) {
        int bf = sniff128(x256);
        float s1 = 0.f, s2 = 0.f;
        for (int j = 0; j < H; ++j) {
            float wc = ldf(W_cell, b * H + j, bf);
            s1 += wc * ldf(Wl, j * H + f, bf);
            s2 += wc * ldf(Wr, j * H + f, bf);
        }
        G1[b * H + f] = s1; G2[b * H + f] = s2;
    } else if (b == 16) {
        int bf = sniff128(x256);
        float s1 = 0.f, s2 = 0.f;
        for (int j = 0; j < H; ++j) {
            float bc = ldf(b_cell, j, bf);
            s1 += bc * ldf(Wl, j * H + f, bf);
            s2 += bc * ldf(Wr, j * H + f, bf);
        }
        g1v[f] = s1; g2v[f] = s2 + ldf(bl, f, bf);
    } else if (b == 17) {
        int bf = sniff128(x256);
        if (f == 0) flag[0] = bf;
    } else {
        // zeroing: counts + mark + ovf_cnt
        for (int i = (b - 18) * 128 + f; i < zero_dw; i += 64 * 128)
            zero_p[i] = 0u;
    }
}

// ---- setup2: blocks 0..24 stage-2 fused weights; blocks 25..229 MLP weight conversion ----
__global__ __launch_bounds__(128) void k_setup2(const float* __restrict__ G1, const float* __restrict__ G2,
                                                const float* __restrict__ g1v, const float* __restrict__ g2v,
                                                const void* __restrict__ Wl_cw,
                                                const void* __restrict__ bl_cw,
                                                const void* __restrict__ Wr_cw,
                                                const void* __restrict__ W_well,
                                                const void* __restrict__ b_well,
                                                const void* __restrict__ Wm1, const void* __restrict__ Wm2,
                                                const void* __restrict__ bm1, const void* __restrict__ bm2,
                                                const int* __restrict__ flag,
                                                float* __restrict__ A1, float* __restrict__ A2,
                                                float* __restrict__ Bm,
                                                float* __restrict__ a1, float* __restrict__ a2,
                                                float* __restrict__ b0,
                                                float* __restrict__ Wm1f, float* __restrict__ Wm2f,
                                                float* __restrict__ bm1f, float* __restrict__ bm2f)
{
    int f = threadIdx.x, b = blockIdx.x, bf = flag[0];
    if (b < 16) {
        float s1 = 0.f, s2 = 0.f;
        for (int j = 0; j < H; ++j) {
            float wl = ldf(Wl_cw, j * H + f, bf);
            s1 += G1[b * H + j] * wl;
            s2 += G2[b * H + j] * wl;
        }
        A1[b * H + f] = s1; A2[b * H + f] = s2;
    } else if (b < 24) {
        int k = b - 16;
        float s = 0.f;
        for (int j = 0; j < H; ++j)
            s += ldf(W_well, k * H + j, bf) * ldf(Wr_cw, j * H + f, bf);
        Bm[k * H + f] = s;
    } else if (b == 24) {
        float s1 = 0.f, s2 = 0.f, s3 = 0.f;
        for (int j = 0; j < H; ++j) {
            float wl = ldf(Wl_cw, j * H + f, bf);
            s1 += g1v[j] * wl;
            s2 += g2v[j] * wl;
            s3 += ldf(b_well, j, bf) * ldf(Wr_cw, j * H + f, bf);
        }
        a1[f] = s1; a2[f] = s2; b0[f] = s3 + ldf(bl_cw, f, bf);
    } else {
        int i = (b - 25) * 128 + f;
        if (i < H * H) Wm1f[i] = ldf(Wm1, i, bf);
        else if (i < H * H + H * OUTF) Wm2f[i - H * H] = ldf(Wm2, i - H * H, bf);
        else if (i < H * H + H * OUTF + H) bm1f[i - H * H - H * OUTF] = ldf(bm1, i - H * H - H * OUTF, bf);
        else if (i < H * H + H * OUTF + H + OUTF) bm2f[i - H * H - H * OUTF - H] = ldf(bm2, i - H * H - H * OUTF - H, bf);
    }
}

// ---- fused: mark cells + well-bucket build (R7 form: 1 edge/thread) ----
__global__ void k_markw(const int* __restrict__ ews, const int* __restrict__ ewd,
                        unsigned char* __restrict__ mark,
                        int* __restrict__ counts_w, int* __restrict__ buckets_w)
{
    int i = blockIdx.x * 256 + threadIdx.x;
    if (i < E_CW) {
        unsigned c = (unsigned)ews[i];
        if (c < N_CELL) mark[c] = 1;
        unsigned d = (unsigned)ewd[i];
        if (d < N_WELL) {
            int s = atomicAdd(&counts_w[d], 1);
            if (s < CAP_W) buckets_w[d * CAP_W + s] = ews[i];
        }
    }
}

// ---- bucket CSR build (R9 form: 4 independent edge-chains/thread — measured 61 vs 68 µs) ----
__global__ __launch_bounds__(256) void k_build(const int* __restrict__ cc_src, const int* __restrict__ cc_dst,
                                               const unsigned char* __restrict__ mark,
                                               int* __restrict__ counts_c,
                                               int* __restrict__ buckets_c,
                                               int* __restrict__ ovf_cnt, int2* __restrict__ ovf)
{
    int i = blockIdx.x * 256 + threadIdx.x;
    int e0 = i, e1 = i + BLD_T, e2 = i + 2 * BLD_T, e3 = i + 3 * BLD_T;
    unsigned d0 = (e0 < E_CC) ? (unsigned)cc_dst[e0] : 0xFFFFFFFFu;
    unsigned d1 = (e1 < E_CC) ? (unsigned)cc_dst[e1] : 0xFFFFFFFFu;
    unsigned d2 = (e2 < E_CC) ? (unsigned)cc_dst[e2] : 0xFFFFFFFFu;
    unsigned d3 = (e3 < E_CC) ? (unsigned)cc_dst[e3] : 0xFFFFFFFFu;
    bool m0 = (d0 < N_CELL) && mark[d0];
    bool m1 = (d1 < N_CELL) && mark[d1];
    bool m2 = (d2 < N_CELL) && mark[d2];
    bool m3 = (d3 < N_CELL) && mark[d3];
    int s0 = m0 ? cc_src[e0] : 0;
    int s1 = m1 ? cc_src[e1] : 0;
    int s2 = m2 ? cc_src[e2] : 0;
    int s3 = m3 ? cc_src[e3] : 0;
    if (m0) {
        int p = atomicAdd(&counts_c[d0], 1);
        if (p < CAP_C) buckets_c[d0 * CAP_C + p] = s0;
        else { int q = atomicAdd(ovf_cnt, 1); if (q < OVF_CAP) { ovf[q].x = (int)d0; ovf[q].y = s0; } }
    }
    if (m1) {
        int p = atomicAdd(&counts_c[d1], 1);
        if (p < CAP_C) buckets_c[d1 * CAP_C + p] = s1;
        else { int q = atomicAdd(ovf_cnt, 1); if (q < OVF_CAP) { ovf[q].x = (int)d1; ovf[q].y = s1; } }
    }
    if (m2) {
        int p = atomicAdd(&counts_c[d2], 1);
        if (p < CAP_C) buckets_c[d2 * CAP_C + p] = s2;
        else { int q = atomicAdd(ovf_cnt, 1); if (q < OVF_CAP) { ovf[q].x = (int)d2; ovf[q].y = s2; } }
    }
    if (m3) {
        int p = atomicAdd(&counts_c[d3], 1);
        if (p < CAP_C) buckets_c[d3 * CAP_C + p] = s3;
        else { int q = atomicAdd(ovf_cnt, 1); if (q < OVF_CAP) { ovf[q].x = (int)d3; ovf[q].y = s3; } }
    }
}

// ---- phase A (R7 form): y[c][16] = mask_c * mean_nbr(x), marked cells only ----
__global__ __launch_bounds__(256) void k_aggA(const void* __restrict__ xr,
                                              const int* __restrict__ flag,
                                              const unsigned char* __restrict__ mark,
                                              const int* __restrict__ counts_c,
                                              const int* __restrict__ buckets_c,
                                              float* __restrict__ y)
{
    int gid = (blockIdx.x * 256 + threadIdx.x) >> 3;
    int jl = threadIdx.x & 7;
    if (gid >= N_CELL) return;
    if (!mark[gid]) return;
    int bf = flag[0];
    int cnt = counts_c[gid]; if (cnt < 0) cnt = 0;
    int lim = (cnt < CAP_C) ? cnt : CAP_C;
    float acc[16];
#pragma unroll
    for (int k = 0; k < 16; ++k) acc[k] = 0.f;

    for (int j = jl; j < lim; j += 8) {
        unsigned s = (unsigned)buckets_c[gid * CAP_C + j]; if (s >= N_CELL) s = 0;
        if (bf) {
            uint4 a = ((const uint4*)xr)[(size_t)s * 2];
            uint4 b = ((const uint4*)xr)[(size_t)s * 2 + 1];
            acc[0] += lo16(a.x);  acc[1] += hi16(a.x);
            acc[2] += lo16(a.y);  acc[3] += hi16(a.y);
            acc[4] += lo16(a.z);  acc[5] += hi16(a.z);
            acc[6] += lo16(a.w);  acc[7] += hi16(a.w);
            acc[8] += lo16(b.x);  acc[9] += hi16(b.x);
            acc[10] += lo16(b.y); acc[11] += hi16(b.y);
            acc[12] += lo16(b.z); acc[13] += hi16(b.z);
            acc[14] += lo16(b.w); acc[15] += hi16(b.w);
        } else {
            const float4* p = (const float4*)xr + (size_t)s * 4;
#pragma unroll
            for (int q = 0; q < 4; ++q) {
                float4 v = p[q];
                acc[4 * q]     += v.x; acc[4 * q + 1] += v.y;
                acc[4 * q + 2] += v.z; acc[4 * q + 3] += v.w;
            }
        }
    }
#pragma unroll
    for (int m = 1; m < 8; m <<= 1) {
#pragma unroll
        for (int k = 0; k < 16; ++k) acc[k] += __shfl_xor(acc[k], m, 64);
    }
    float sc = (cnt > 0) ? (1.0f / (float)cnt) : 0.0f;
    float2 st; st.x = acc[2 * jl] * sc; st.y = acc[2 * jl + 1] * sc;
    ((float2*)y)[(size_t)gid * 8 + jl] = st;
}

// ---- fold overflow edges (deg>CAP_C) into y ----
__global__ __launch_bounds__(256) void k_ovf(const void* __restrict__ xr,
                                             const int* __restrict__ flag,
                                             const int* __restrict__ ovf_cnt,
                                             const int2* __restrict__ ovf,
                                             const int* __restrict__ counts_c,
                                             float* __restrict__ y)
{
    int gid = (blockIdx.x * 256 + threadIdx.x) >> 3;
    int jl = threadIdx.x & 7;
    int n = ovf_cnt[0]; if (n > OVF_CAP) n = OVF_CAP;
    if (gid >= n) return;
    int bf = flag[0];
    unsigned d = (unsigned)ovf[gid].x; if (d >= N_CELL) d = 0;
    unsigned s = (unsigned)ovf[gid].y; if (s >= N_CELL) s = 0;
    int cnt = counts_c[d];
    float inv = (cnt > 0) ? (1.0f / (float)cnt) : 0.0f;
    float v0, v1;
    if (bf) {
        unsigned int u = ((const unsigned int*)xr)[(size_t)s * 8 + jl];
        v0 = lo16(u); v1 = hi16(u);
    } else {
        v0 = ((const float*)xr)[(size_t)s * 16 + 2 * jl];
        v1 = ((const float*)xr)[(size_t)s * 16 + 2 * jl + 1];
    }
    atomicAdd(&y[(size_t)d * 16 + 2 * jl], v0 * inv);
    atomicAdd(&y[(size_t)d * 16 + 2 * jl + 1], v1 * inv);
}

// ---- per-well aggregation + folded SAGE-cw (proven) ----
__global__ __launch_bounds__(256) void k_wellagg(const void* __restrict__ xr,
                                                 const int* __restrict__ flag,
                                                 const float* __restrict__ y,
                                                 const int* __restrict__ counts_c,
                                                 const int* __restrict__ counts_w,
                                                 const int* __restrict__ buckets_w,
                                                 const void* __restrict__ wx,
                                                 const float* __restrict__ A1, const float* __restrict__ A2,
                                                 const float* __restrict__ Bm,
                                                 const float* __restrict__ a1, const float* __restrict__ a2,
                                                 const float* __restrict__ b0,
                                                 float* __restrict__ Z)
{
    __shared__ float sP[16], sR[16], sq[1];
    int w = blockIdx.x, t = threadIdx.x, bf = flag[0];
    int g = t >> 3, jl = t & 7;
    if (t < 16) { sP[t] = 0.f; sR[t] = 0.f; }
    if (t == 16) sq[0] = 0.f;
    __syncthreads();

    int cntw = counts_w[w]; if (cntw < 0) cntw = 0;
    int lim = (cntw < CAP_W) ? cntw : CAP_W;

    float p0 = 0.f, p1 = 0.f, r0 = 0.f, r1 = 0.f, qn = 0.f;
    const unsigned int* x32 = (const unsigned int*)xr;
    const float* xf = (const float*)xr;

    for (int e = g; e < lim; e += 32) {
        unsigned c = (unsigned)buckets_w[w * CAP_W + e]; if (c >= N_CELL) c = 0;
        float2 yv = ((const float2*)y)[(size_t)c * 8 + jl];
        p0 += yv.x; p1 += yv.y;
        if (bf) {
            unsigned int u = x32[(size_t)c * 8 + jl];
            r0 += lo16(u); r1 += hi16(u);
        } else {
            r0 += xf[(size_t)c * 16 + 2 * jl];
            r1 += xf[(size_t)c * 16 + 2 * jl + 1];
        }
        if (jl == 0) qn += (counts_c[c] > 0) ? 1.0f : 0.0f;
    }
    atomicAdd(&sP[2 * jl], p0);
    atomicAdd(&sP[2 * jl + 1], p1);
    atomicAdd(&sR[2 * jl], r0);
    atomicAdd(&sR[2 * jl + 1], r1);
    if (jl == 0 && qn != 0.f) atomicAdd(&sq[0], qn);
    __syncthreads();

    int f = t;
    if (f < H) {
        float inv = (cntw > 0) ? (1.0f / (float)cntw) : 0.0f;
        float mask = (cntw > 0) ? 1.0f : 0.0f;
        float wh = (sq[0] * inv) * a1[f] + a2[f];
#pragma unroll
        for (int k = 0; k < 16; ++k)
            wh += (sP[k] * inv) * A1[k * H + f] + (sR[k] * inv) * A2[k * H + f];
        wh *= mask;
        wh += b0[f];
#pragma unroll
        for (int k = 0; k < WF; ++k)
            wh += ldf(wx, w * WF + k, bf) * Bm[k * H + f];
        Z[(size_t)w * H + f] = wh;
    }
}

// ---- batched MLP head (proven) ----
__global__ __launch_bounds__(128) void k_head(const float* __restrict__ Z,
                                              const float* __restrict__ Wm1f, const float* __restrict__ Wm2f,
                                              const float* __restrict__ bm1f, const float* __restrict__ bm2f,
                                              const int* __restrict__ flag,
                                              void* __restrict__ outp)
{
    __shared__ float sz[WPB][H], sh[WPB][H];
    int w0 = blockIdx.x * WPB, t = threadIdx.x, bf = flag[0];
    float4 zv = ((const float4*)(Z + (size_t)w0 * H))[t];
    ((float4*)&sz[0][0])[t] = zv;
    __syncthreads();

    float acc[WPB];
#pragma unroll
    for (int i = 0; i < WPB; ++i) acc[i] = bm1f[t];
    for (int k = 0; k < H; ++k) {
        float wm = Wm1f[k * H + t];
#pragma unroll
        for (int i = 0; i < WPB; ++i) acc[i] += sz[i][k] * wm;
    }
#pragma unroll
    for (int i = 0; i < WPB; ++i) sh[i][t] = fmaxf(acc[i], 0.f);
    __syncthreads();

    if (t < OUTF) {
        float o[WPB];
#pragma unroll
        for (int i = 0; i < WPB; ++i) o[i] = bm2f[t];
        for (int k = 0; k < H; ++k) {
            float wm = Wm2f[k * OUTF + t];
#pragma unroll
            for (int i = 0; i < WPB; ++i) o[i] += sh[i][k] * wm;
        }
        if (bf) {
#pragma unroll
            for (int i = 0; i < WPB; ++i)
                ((unsigned short*)outp)[(size_t)(w0 + i) * OUTF + t] = f2b(o[i]);
        } else {
#pragma unroll
            for (int i = 0; i < WPB; ++i)
                ((float*)outp)[(size_t)(w0 + i) * OUTF + t] = o[i];
        }
    }
}

extern "C" void kernel_launch(void* const* d_in, const int* in_sizes, int n_in,
                              void* d_out, int out_size, void* d_ws, size_t ws_size,
                              hipStream_t stream)
{
    const void* cell_x = d_in[0];
    const void* well_x = d_in[1];
    const int* eic = (const int*)d_in[2];
    const int* ews = (const int*)d_in[3];
    const int* ewd = (const int*)d_in[4];
    const void* W_cell = d_in[5];
    const void* b_cell = d_in[6];
    const void* W_well = d_in[7];
    const void* b_well = d_in[8];
    const void* Wl_cc = d_in[9];
    const void* bl_cc = d_in[10];
    const void* Wr_cc = d_in[11];
    const void* Wl_cw = d_in[12];
    const void* bl_cw = d_in[13];
    const void* Wr_cw = d_in[14];
    const void* W_m1 = d_in[15];
    const void* b_m1 = d_in[16];
    const void* W_m2 = d_in[17];
    const void* b_m2 = d_in[18];
    (void)in_sizes; (void)n_in; (void)out_size; (void)ws_size;

    const int* cc_src = eic;
    const int* cc_dst = eic + E_CC;

    char* wsp = (char*)d_ws;
    size_t off = 0;
    auto carve = [&](size_t bytes) -> char* {
        char* p = wsp + off;
        off = (off + bytes + 255) & ~(size_t)255;
        return p;
    };

    // small fused-weight buffers
    float* G1   = (float*)carve(16 * H * 4);
    float* G2   = (float*)carve(16 * H * 4);
    float* g1v  = (float*)carve(H * 4);
    float* g2v  = (float*)carve(H * 4);
    float* A1   = (float*)carve(16 * H * 4);
    float* A2   = (float*)carve(16 * H * 4);
    float* Bm   = (float*)carve(WF * H * 4);
    float* a1   = (float*)carve(H * 4);
    float* a2   = (float*)carve(H * 4);
    float* b0   = (float*)carve(H * 4);
    float* Wm1f = (float*)carve(H * H * 4);
    float* Wm2f = (float*)carve(H * OUTF * 4);
    float* bm1f = (float*)carve(H * 4);
    float* bm2f = (float*)carve(OUTF * 4);
    int*   flag = (int*)carve(256);
    // zero region (cleared by k_setup1 blocks 18+): counts + mark + ovf_cnt
    size_t zero_beg = off;
    int*   counts   = (int*)carve((size_t)(N_CELL + N_WELL) * 4);
    int*   counts_c = counts;
    int*   counts_w = counts + N_CELL;
    unsigned char* mark = (unsigned char*)carve((size_t)N_CELL);
    int*   ovf_cnt  = (int*)carve(256);
    size_t zero_end = off;
    // big buffers (~29.5 MB; ws proven >= ~35 MB in R5/R6)
    int*   buckets_c = (int*)carve((size_t)N_CELL * CAP_C * 4);   // 12.8 MB
    int*   buckets_w = (int*)carve((size_t)N_WELL * CAP_W * 4);   // 1.8 MB
    float* y         = (float*)carve((size_t)N_CELL * 16 * 4);    // 12.8 MB
    int2*  ovf       = (int2*)carve((size_t)OVF_CAP * 8);         // 128 KB
    float* Z         = (float*)carve((size_t)N_WELL * H * 4);     // 1 MB

    int zero_dw = (int)((zero_end - zero_beg) / 4);

    // 1. setup1: sniff (per-block) + stage-1 precomp + flag + zeroing  [1 dispatch]
    k_setup1<<<82, 128, 0, stream>>>((const unsigned int*)cell_x, W_cell, b_cell, Wl_cc, Wr_cc, bl_cc,
                                     G1, G2, g1v, g2v, flag,
                                     (unsigned int*)((char*)d_ws + zero_beg), zero_dw);
    // 2. setup2: stage-2 fused weights + MLP weight conversion  [1 dispatch]
    k_setup2<<<230, 128, 0, stream>>>(G1, G2, g1v, g2v, Wl_cw, bl_cw, Wr_cw, W_well, b_well,
                                      W_m1, W_m2, b_m1, b_m2, flag,
                                      A1, A2, Bm, a1, a2, b0, Wm1f, Wm2f, bm1f, bm2f);
    // 3. mark + well buckets
    k_markw<<<(E_CW + 255) / 256, 256, 0, stream>>>(ews, ewd, mark, counts_w, buckets_w);
    // 4. cell buckets
    k_build<<<BLD_T / 256, 256, 0, stream>>>(cc_src, cc_dst, mark, counts_c, buckets_c, ovf_cnt, ovf);
    // 5. per-cell 16-dim means
    k_aggA<<<(N_CELL * 8 + 255) / 256, 256, 0, stream>>>(cell_x, flag, mark, counts_c, buckets_c, y);
    // 6. overflow fold
    k_ovf<<<(OVF_CAP * 8 + 255) / 256, 256, 0, stream>>>(cell_x, flag, ovf_cnt, ovf, counts_c, y);
    // 7. per-well aggregation + folded SAGE
    k_wellagg<<<N_WELL, 256, 0, stream>>>(cell_x, flag, y, counts_c, counts_w, buckets_w,
                                          well_x, A1, A2, Bm, a1, a2, b0, Z);
    // 8. batched MLP head
    k_head<<<N_WELL / WPB, 128, 0, stream>>>(Z, Wm1f, Wm2f, bm1f, bm2f, flag, d_out);
}

// Round 11
// 274.786 us; speedup vs baseline: 1.3379x; 1.0542x over previous
//
#include <hip/hip_runtime.h>

#define N_CELL 200000
#define N_WELL 2000
#define E_CC   1200000
#define E_CW   200000
#define CF     16
#define WF     8
#define H      128
#define OUTF   75

#define CAP_C  16           // bucket row = exactly one 64B line; overflow -> side list
#define CAP_W  224          // bucket capacity per well (deg ~ Poisson(100))
#define OVF_CAP 16384
#define WPB    4            // wells per block in k_head

#define NCHUNK 150          // edge chunks for k_build
#define BCHUNK 8000         // E_CC / NCHUNK

__device__ __forceinline__ float b2f(unsigned short u) {
    union { unsigned int i; float f; } v; v.i = ((unsigned int)u) << 16; return v.f;
}
__device__ __forceinline__ unsigned short f2b(float f) {
    union { float f; unsigned int i; } v; v.f = f;
    unsigned int i = v.i;
    return (unsigned short)((i + 0x7fffu + ((i >> 16) & 1u)) >> 16);  // RNE
}
__device__ __forceinline__ float lo16(unsigned int v) { return b2f((unsigned short)(v & 0xffffu)); }
__device__ __forceinline__ float hi16(unsigned int v) { return b2f((unsigned short)(v >> 16)); }
__device__ __forceinline__ float ldf(const void* p, int i, int bf) {
    return bf ? b2f(((const unsigned short*)p)[i]) : ((const float*)p)[i];
}

// per-block inline dtype sniff (128 threads): no cross-block dependency
__device__ __forceinline__ int sniff128(const unsigned int* __restrict__ x)
{
    __shared__ int cnt[128];
    int t = threadIdx.x;
    unsigned a = x[t], b = x[t + 128];
    unsigned ea = (a >> 7) & 0xffu, eb = (b >> 7) & 0xffu;
    cnt[t] = ((ea >= 110u && ea <= 135u) ? 1 : 0) + ((eb >= 110u && eb <= 135u) ? 1 : 0);
    __syncthreads();
    for (int o = 64; o > 0; o >>= 1) { if (t < o) cnt[t] += cnt[t + o]; __syncthreads(); }
    int r = (cnt[0] >= 192) ? 1 : 0;
    __syncthreads();
    return r;
}

// ---- setup1: blocks 0..16 stage-1 precomp (inline sniff); block 17 flag store; blocks 18..81 zeroing ----
__global__ __launch_bounds__(128) void k_setup1(const unsigned int* __restrict__ x256,
                                                const void* __restrict__ W_cell,
                                                const void* __restrict__ b_cell,
                                                const void* __restrict__ Wl,
                                                const void* __restrict__ Wr,
                                                const void* __restrict__ bl,
                                                float* __restrict__ G1, float* __restrict__ G2,
                                                float* __restrict__ g1v, float* __restrict__ g2v,
                                                int* __restrict__ flag,
                                                unsigned int* __restrict__ zero_p, int zero_dw)
{
    int f = threadIdx.x, b = blockIdx.x;
    if (b < 16) {
        int bf = sniff128(x256);
        float s1 = 0.f, s2 = 0.f;
        for (int j = 0; j < H; ++j) {
            float wc = ldf(W_cell, b * H + j, bf);
            s1 += wc * ldf(Wl, j * H + f, bf);
            s2 += wc * ldf(Wr, j * H + f, bf);
        }
        G1[b * H + f] = s1; G2[b * H + f] = s2;
    } else if (b == 16) {
        int bf = sniff128(x256);
        float s1 = 0.f, s2 = 0.f;
        for (int j = 0; j < H; ++j) {
            float bc = ldf(b_cell, j, bf);
            s1 += bc * ldf(Wl, j * H + f, bf);
            s2 += bc * ldf(Wr, j * H + f, bf);
        }
        g1v[f] = s1; g2v[f] = s2 + ldf(bl, f, bf);
    } else if (b == 17) {
        int bf = sniff128(x256);
        if (f == 0) flag[0] = bf;
    } else {
        for (int i = (b - 18) * 128 + f; i < zero_dw; i += 64 * 128)
            zero_p[i] = 0u;
    }
}

// ---- setup2: blocks 0..24 stage-2 fused weights; blocks 25..229 MLP weight conversion ----
__global__ __launch_bounds__(128) void k_setup2(const float* __restrict__ G1, const float* __restrict__ G2,
                                                const float* __restrict__ g1v, const float* __restrict__ g2v,
                                                const void* __restrict__ Wl_cw,
                                                const void* __restrict__ bl_cw,
                                                const void* __restrict__ Wr_cw,
                                                const void* __restrict__ W_well,
                                                const void* __restrict__ b_well,
                                                const void* __restrict__ Wm1, const void* __restrict__ Wm2,
                                                const void* __restrict__ bm1, const void* __restrict__ bm2,
                                                const int* __restrict__ flag,
                                                float* __restrict__ A1, float* __restrict__ A2,
                                                float* __restrict__ Bm,
                                                float* __restrict__ a1, float* __restrict__ a2,
                                                float* __restrict__ b0,
                                                float* __restrict__ Wm1f, float* __restrict__ Wm2f,
                                                float* __restrict__ bm1f, float* __restrict__ bm2f)
{
    int f = threadIdx.x, b = blockIdx.x, bf = flag[0];
    if (b < 16) {
        float s1 = 0.f, s2 = 0.f;
        for (int j = 0; j < H; ++j) {
            float wl = ldf(Wl_cw, j * H + f, bf);
            s1 += G1[b * H + j] * wl;
            s2 += G2[b * H + j] * wl;
        }
        A1[b * H + f] = s1; A2[b * H + f] = s2;
    } else if (b < 24) {
        int k = b - 16;
        float s = 0.f;
        for (int j = 0; j < H; ++j)
            s += ldf(W_well, k * H + j, bf) * ldf(Wr_cw, j * H + f, bf);
        Bm[k * H + f] = s;
    } else if (b == 24) {
        float s1 = 0.f, s2 = 0.f, s3 = 0.f;
        for (int j = 0; j < H; ++j) {
            float wl = ldf(Wl_cw, j * H + f, bf);
            s1 += g1v[j] * wl;
            s2 += g2v[j] * wl;
            s3 += ldf(b_well, j, bf) * ldf(Wr_cw, j * H + f, bf);
        }
        a1[f] = s1; a2[f] = s2; b0[f] = s3 + ldf(bl_cw, f, bf);
    } else {
        int i = (b - 25) * 128 + f;
        if (i < H * H) Wm1f[i] = ldf(Wm1, i, bf);
        else if (i < H * H + H * OUTF) Wm2f[i - H * H] = ldf(Wm2, i - H * H, bf);
        else if (i < H * H + H * OUTF + H) bm1f[i - H * H - H * OUTF] = ldf(bm1, i - H * H - H * OUTF, bf);
        else if (i < H * H + H * OUTF + H + OUTF) bm2f[i - H * H - H * OUTF - H] = ldf(bm2, i - H * H - H * OUTF - H, bf);
    }
}

// ---- fused: mark cells + well-bucket build (R7 form: 1 edge/thread) ----
__global__ void k_markw(const int* __restrict__ ews, const int* __restrict__ ewd,
                        unsigned char* __restrict__ mark,
                        int* __restrict__ counts_w, int* __restrict__ buckets_w)
{
    int i = blockIdx.x * 256 + threadIdx.x;
    if (i < E_CW) {
        unsigned c = (unsigned)ews[i];
        if (c < N_CELL) mark[c] = 1;
        unsigned d = (unsigned)ewd[i];
        if (d < N_WELL) {
            int s = atomicAdd(&counts_w[d], 1);
            if (s < CAP_W) buckets_w[d * CAP_W + s] = ews[i];
        }
    }
}

// ---- bucket CSR build, XCD-affinity routed: block (xcd=blk&7, chunk=blk>>3) scans its
// chunk and commits only edges whose dst routing-group (dst>>5)&7 == xcd. Bucket/counter
// lines become single-XCD-owned (round-robin blockIdx->XCD heuristic) -> 1 writeback/line.
__global__ __launch_bounds__(256) void k_build(const int* __restrict__ cc_src, const int* __restrict__ cc_dst,
                                               const unsigned char* __restrict__ mark,
                                               int* __restrict__ counts_c,
                                               int* __restrict__ buckets_c,
                                               int* __restrict__ ovf_cnt, int2* __restrict__ ovf)
{
    int xcd = blockIdx.x & 7;
    int cb  = blockIdx.x >> 3;
    int beg = cb * BCHUNK, end = beg + BCHUNK;
    if (end > E_CC) end = E_CC;
    for (int e = beg + threadIdx.x; e < end; e += 256) {
        unsigned d = (unsigned)cc_dst[e];
        if (d < N_CELL && (int)((d >> 5) & 7u) == xcd && mark[d]) {
            int s = cc_src[e];
            int p = atomicAdd(&counts_c[d], 1);
            if (p < CAP_C) buckets_c[d * CAP_C + p] = s;
            else { int q = atomicAdd(ovf_cnt, 1); if (q < OVF_CAP) { ovf[q].x = (int)d; ovf[q].y = s; } }
        }
    }
}

// ---- phase A (R7 form): y[c][16] = mask_c * mean_nbr(x), marked cells only.
// Block b covers cells 32b..32b+31 = routing group b -> same XCD as k_build's commits.
__global__ __launch_bounds__(256) void k_aggA(const void* __restrict__ xr,
                                              const int* __restrict__ flag,
                                              const unsigned char* __restrict__ mark,
                                              const int* __restrict__ counts_c,
                                              const int* __restrict__ buckets_c,
                                              float* __restrict__ y)
{
    int gid = (blockIdx.x * 256 + threadIdx.x) >> 3;
    int jl = threadIdx.x & 7;
    if (gid >= N_CELL) return;
    if (!mark[gid]) return;
    int bf = flag[0];
    int cnt = counts_c[gid]; if (cnt < 0) cnt = 0;
    int lim = (cnt < CAP_C) ? cnt : CAP_C;
    float acc[16];
#pragma unroll
    for (int k = 0; k < 16; ++k) acc[k] = 0.f;

    for (int j = jl; j < lim; j += 8) {
        unsigned s = (unsigned)buckets_c[gid * CAP_C + j]; if (s >= N_CELL) s = 0;
        if (bf) {
            uint4 a = ((const uint4*)xr)[(size_t)s * 2];
            uint4 b = ((const uint4*)xr)[(size_t)s * 2 + 1];
            acc[0] += lo16(a.x);  acc[1] += hi16(a.x);
            acc[2] += lo16(a.y);  acc[3] += hi16(a.y);
            acc[4] += lo16(a.z);  acc[5] += hi16(a.z);
            acc[6] += lo16(a.w);  acc[7] += hi16(a.w);
            acc[8] += lo16(b.x);  acc[9] += hi16(b.x);
            acc[10] += lo16(b.y); acc[11] += hi16(b.y);
            acc[12] += lo16(b.z); acc[13] += hi16(b.z);
            acc[14] += lo16(b.w); acc[15] += hi16(b.w);
        } else {
            const float4* p = (const float4*)xr + (size_t)s * 4;
#pragma unroll
            for (int q = 0; q < 4; ++q) {
                float4 v = p[q];
                acc[4 * q]     += v.x; acc[4 * q + 1] += v.y;
                acc[4 * q + 2] += v.z; acc[4 * q + 3] += v.w;
            }
        }
    }
#pragma unroll
    for (int m = 1; m < 8; m <<= 1) {
#pragma unroll
        for (int k = 0; k < 16; ++k) acc[k] += __shfl_xor(acc[k], m, 64);
    }
    float sc = (cnt > 0) ? (1.0f / (float)cnt) : 0.0f;
    float2 st; st.x = acc[2 * jl] * sc; st.y = acc[2 * jl + 1] * sc;
    ((float2*)y)[(size_t)gid * 8 + jl] = st;
}

// ---- fold overflow edges (deg>CAP_C) into y ----
__global__ __launch_bounds__(256) void k_ovf(const void* __restrict__ xr,
                                             const int* __restrict__ flag,
                                             const int* __restrict__ ovf_cnt,
                                             const int2* __restrict__ ovf,
                                             const int* __restrict__ counts_c,
                                             float* __restrict__ y)
{
    int gid = (blockIdx.x * 256 + threadIdx.x) >> 3;
    int jl = threadIdx.x & 7;
    int n = ovf_cnt[0]; if (n > OVF_CAP) n = OVF_CAP;
    if (gid >= n) return;
    int bf = flag[0];
    unsigned d = (unsigned)ovf[gid].x; if (d >= N_CELL) d = 0;
    unsigned s = (unsigned)ovf[gid].y; if (s >= N_CELL) s = 0;
    int cnt = counts_c[d];
    float inv = (cnt > 0) ? (1.0f / (float)cnt) : 0.0f;
    float v0, v1;
    if (bf) {
        unsigned int u = ((const unsigned int*)xr)[(size_t)s * 8 + jl];
        v0 = lo16(u); v1 = hi16(u);
    } else {
        v0 = ((const float*)xr)[(size_t)s * 16 + 2 * jl];
        v1 = ((const float*)xr)[(size_t)s * 16 + 2 * jl + 1];
    }
    atomicAdd(&y[(size_t)d * 16 + 2 * jl], v0 * inv);
    atomicAdd(&y[(size_t)d * 16 + 2 * jl + 1], v1 * inv);
}

// ---- per-well aggregation + folded SAGE-cw (proven) ----
__global__ __launch_bounds__(256) void k_wellagg(const void* __restrict__ xr,
                                                 const int* __restrict__ flag,
                                                 const float* __restrict__ y,
                                                 const int* __restrict__ counts_c,
                                                 const int* __restrict__ counts_w,
                                                 const int* __restrict__ buckets_w,
                                                 const void* __restrict__ wx,
                                                 const float* __restrict__ A1, const float* __restrict__ A2,
                                                 const float* __restrict__ Bm,
                                                 const float* __restrict__ a1, const float* __restrict__ a2,
                                                 const float* __restrict__ b0,
                                                 float* __restrict__ Z)
{
    __shared__ float sP[16], sR[16], sq[1];
    int w = blockIdx.x, t = threadIdx.x, bf = flag[0];
    int g = t >> 3, jl = t & 7;
    if (t < 16) { sP[t] = 0.f; sR[t] = 0.f; }
    if (t == 16) sq[0] = 0.f;
    __syncthreads();

    int cntw = counts_w[w]; if (cntw < 0) cntw = 0;
    int lim = (cntw < CAP_W) ? cntw : CAP_W;

    float p0 = 0.f, p1 = 0.f, r0 = 0.f, r1 = 0.f, qn = 0.f;
    const unsigned int* x32 = (const unsigned int*)xr;
    const float* xf = (const float*)xr;

    for (int e = g; e < lim; e += 32) {
        unsigned c = (unsigned)buckets_w[w * CAP_W + e]; if (c >= N_CELL) c = 0;
        float2 yv = ((const float2*)y)[(size_t)c * 8 + jl];
        p0 += yv.x; p1 += yv.y;
        if (bf) {
            unsigned int u = x32[(size_t)c * 8 + jl];
            r0 += lo16(u); r1 += hi16(u);
        } else {
            r0 += xf[(size_t)c * 16 + 2 * jl];
            r1 += xf[(size_t)c * 16 + 2 * jl + 1];
        }
        if (jl == 0) qn += (counts_c[c] > 0) ? 1.0f : 0.0f;
    }
    atomicAdd(&sP[2 * jl], p0);
    atomicAdd(&sP[2 * jl + 1], p1);
    atomicAdd(&sR[2 * jl], r0);
    atomicAdd(&sR[2 * jl + 1], r1);
    if (jl == 0 && qn != 0.f) atomicAdd(&sq[0], qn);
    __syncthreads();

    int f = t;
    if (f < H) {
        float inv = (cntw > 0) ? (1.0f / (float)cntw) : 0.0f;
        float mask = (cntw > 0) ? 1.0f : 0.0f;
        float wh = (sq[0] * inv) * a1[f] + a2[f];
#pragma unroll
        for (int k = 0; k < 16; ++k)
            wh += (sP[k] * inv) * A1[k * H + f] + (sR[k] * inv) * A2[k * H + f];
        wh *= mask;
        wh += b0[f];
#pragma unroll
        for (int k = 0; k < WF; ++k)
            wh += ldf(wx, w * WF + k, bf) * Bm[k * H + f];
        Z[(size_t)w * H + f] = wh;
    }
}

// ---- batched MLP head (proven) ----
__global__ __launch_bounds__(128) void k_head(const float* __restrict__ Z,
                                              const float* __restrict__ Wm1f, const float* __restrict__ Wm2f,
                                              const float* __restrict__ bm1f, const float* __restrict__ bm2f,
                                              const int* __restrict__ flag,
                                              void* __restrict__ outp)
{
    __shared__ float sz[WPB][H], sh[WPB][H];
    int w0 = blockIdx.x * WPB, t = threadIdx.x, bf = flag[0];
    float4 zv = ((const float4*)(Z + (size_t)w0 * H))[t];
    ((float4*)&sz[0][0])[t] = zv;
    __syncthreads();

    float acc[WPB];
#pragma unroll
    for (int i = 0; i < WPB; ++i) acc[i] = bm1f[t];
    for (int k = 0; k < H; ++k) {
        float wm = Wm1f[k * H + t];
#pragma unroll
        for (int i = 0; i < WPB; ++i) acc[i] += sz[i][k] * wm;
    }
#pragma unroll
    for (int i = 0; i < WPB; ++i) sh[i][t] = fmaxf(acc[i], 0.f);
    __syncthreads();

    if (t < OUTF) {
        float o[WPB];
#pragma unroll
        for (int i = 0; i < WPB; ++i) o[i] = bm2f[t];
        for (int k = 0; k < H; ++k) {
            float wm = Wm2f[k * OUTF + t];
#pragma unroll
            for (int i = 0; i < WPB; ++i) o[i] += sh[i][k] * wm;
        }
        if (bf) {
#pragma unroll
            for (int i = 0; i < WPB; ++i)
                ((unsigned short*)outp)[(size_t)(w0 + i) * OUTF + t] = f2b(o[i]);
        } else {
#pragma unroll
            for (int i = 0; i < WPB; ++i)
                ((float*)outp)[(size_t)(w0 + i) * OUTF + t] = o[i];
        }
    }
}

extern "C" void kernel_launch(void* const* d_in, const int* in_sizes, int n_in,
                              void* d_out, int out_size, void* d_ws, size_t ws_size,
                              hipStream_t stream)
{
    const void* cell_x = d_in[0];
    const void* well_x = d_in[1];
    const int* eic = (const int*)d_in[2];
    const int* ews = (const int*)d_in[3];
    const int* ewd = (const int*)d_in[4];
    const void* W_cell = d_in[5];
    const void* b_cell = d_in[6];
    const void* W_well = d_in[7];
    const void* b_well = d_in[8];
    const void* Wl_cc = d_in[9];
    const void* bl_cc = d_in[10];
    const void* Wr_cc = d_in[11];
    const void* Wl_cw = d_in[12];
    const void* bl_cw = d_in[13];
    const void* Wr_cw = d_in[14];
    const void* W_m1 = d_in[15];
    const void* b_m1 = d_in[16];
    const void* W_m2 = d_in[17];
    const void* b_m2 = d_in[18];
    (void)in_sizes; (void)n_in; (void)out_size; (void)ws_size;

    const int* cc_src = eic;
    const int* cc_dst = eic + E_CC;

    char* wsp = (char*)d_ws;
    size_t off = 0;
    auto carve = [&](size_t bytes) -> char* {
        char* p = wsp + off;
        off = (off + bytes + 255) & ~(size_t)255;
        return p;
    };

    // small fused-weight buffers
    float* G1   = (float*)carve(16 * H * 4);
    float* G2   = (float*)carve(16 * H * 4);
    float* g1v  = (float*)carve(H * 4);
    float* g2v  = (float*)carve(H * 4);
    float* A1   = (float*)carve(16 * H * 4);
    float* A2   = (float*)carve(16 * H * 4);
    float* Bm   = (float*)carve(WF * H * 4);
    float* a1   = (float*)carve(H * 4);
    float* a2   = (float*)carve(H * 4);
    float* b0   = (float*)carve(H * 4);
    float* Wm1f = (float*)carve(H * H * 4);
    float* Wm2f = (float*)carve(H * OUTF * 4);
    float* bm1f = (float*)carve(H * 4);
    float* bm2f = (float*)carve(OUTF * 4);
    int*   flag = (int*)carve(256);
    // zero region (cleared by k_setup1 blocks 18+): counts + mark + ovf_cnt
    size_t zero_beg = off;
    int*   counts   = (int*)carve((size_t)(N_CELL + N_WELL) * 4);
    int*   counts_c = counts;
    int*   counts_w = counts + N_CELL;
    unsigned char* mark = (unsigned char*)carve((size_t)N_CELL);
    int*   ovf_cnt  = (int*)carve(256);
    size_t zero_end = off;
    // big buffers (~29.5 MB; ws proven >= ~35 MB in R5/R6)
    int*   buckets_c = (int*)carve((size_t)N_CELL * CAP_C * 4);   // 12.8 MB
    int*   buckets_w = (int*)carve((size_t)N_WELL * CAP_W * 4);   // 1.8 MB
    float* y         = (float*)carve((size_t)N_CELL * 16 * 4);    // 12.8 MB
    int2*  ovf       = (int2*)carve((size_t)OVF_CAP * 8);         // 128 KB
    float* Z         = (float*)carve((size_t)N_WELL * H * 4);     // 1 MB

    int zero_dw = (int)((zero_end - zero_beg) / 4);

    // 1. setup1: sniff (per-block) + stage-1 precomp + flag + zeroing
    k_setup1<<<82, 128, 0, stream>>>((const unsigned int*)cell_x, W_cell, b_cell, Wl_cc, Wr_cc, bl_cc,
                                     G1, G2, g1v, g2v, flag,
                                     (unsigned int*)((char*)d_ws + zero_beg), zero_dw);
    // 2. setup2: stage-2 fused weights + MLP weight conversion
    k_setup2<<<230, 128, 0, stream>>>(G1, G2, g1v, g2v, Wl_cw, bl_cw, Wr_cw, W_well, b_well,
                                      W_m1, W_m2, b_m1, b_m2, flag,
                                      A1, A2, Bm, a1, a2, b0, Wm1f, Wm2f, bm1f, bm2f);
    // 3. mark + well buckets
    k_markw<<<(E_CW + 255) / 256, 256, 0, stream>>>(ews, ewd, mark, counts_w, buckets_w);
    // 4. cell buckets (XCD-affinity routed)
    k_build<<<8 * NCHUNK, 256, 0, stream>>>(cc_src, cc_dst, mark, counts_c, buckets_c, ovf_cnt, ovf);
    // 5. per-cell 16-dim means
    k_aggA<<<(N_CELL * 8 + 255) / 256, 256, 0, stream>>>(cell_x, flag, mark, counts_c, buckets_c, y);
    // 6. overflow fold
    k_ovf<<<(OVF_CAP * 8 + 255) / 256, 256, 0, stream>>>(cell_x, flag, ovf_cnt, ovf, counts_c, y);
    // 7. per-well aggregation + folded SAGE
    k_wellagg<<<N_WELL, 256, 0, stream>>>(cell_x, flag, y, counts_c, counts_w, buckets_w,
                                          well_x, A1, A2, Bm, a1, a2, b0, Z);
    // 8. batched MLP head
    k_head<<<N_WELL / WPB, 128, 0, stream>>>(Z, Wm1f, Wm2f, bm1f, bm2f, flag, d_out);
}